// Round 2
// baseline (3636.942 us; speedup 1.0000x reference)
//
#include <hip/hip_runtime.h>
#include <math.h>

#define DEV static __device__ __forceinline__

// ---- problem constants ----
#define B_   2
#define N_   4
#define T_   512
#define D_   1024
#define DK_  64
#define H_   8
#define E_   6
#define DV_  64
#define DKP_ 128
#define HE_  48
#define R_   16
#define DA_  103
#define CC_  512
#define DPG_ 316
#define ND_  4096
#define U_   1024      // B*T tokens

struct P {
  // inputs
  const float *stream, *freqs, *pope_delta;
  const float *W_q, *W_k, *W_v, *q_rw, *kv_rw;
  const float *lA_q, *lB_q, *lA_k, *lB_k, *lA_v, *lB_v;
  const float *a_up, *a_dn, *b_up, *b_dn;
  const float *mhc_norm, *phi_pre, *phi_post, *phi_res;
  const float *b_pre, *b_post, *b_res, *al_pre, *al_post, *al_res;
  const float *bn_w, *W_pre, *W_o, *W_pg1, *W_pg2;
  // workspace
  int *qsel, *kvsel, *qcnt, *kvcnt, *qlist, *kvlist;
  float *scale, *phiT, *mhc_partial;
  float *Hpre_q, *Hpre_kv, *Hres, *Hpost;
  float *he_kv, *he_q;
  float *WqT, *WkT, *WvT, *WoT;
  float *kv_lin, *aup, *bup, *pre_logit, *pg, *post_logit;
  float *la_k, *la_v, *la_q, *q_lin;
  float *a_buf, *b_buf, *q_buf, *k_buf, *v_buf;
  float *attn, *y;
  float *out;
};

DEV float sigm(float x){ return 1.f/(1.f+expf(-x)); }
DEV float softplus_(float x){ return x>0.f ? x+log1pf(expf(-x)) : log1pf(expf(x)); }
DEV float silu_(float x){ return x*sigm(x); }

DEV float block_reduce_sum(float v, float* sm){
  __syncthreads();
  int lane = threadIdx.x & 63, w = threadIdx.x >> 6;
  for (int off=32; off; off>>=1) v += __shfl_down(v, off, 64);
  if (lane==0) sm[w] = v;
  __syncthreads();
  if (threadIdx.x == 0){
    float s = 0; int nw = blockDim.x >> 6;
    for (int i=0;i<nw;i++) s += sm[i];
    sm[0] = s;
  }
  __syncthreads();
  return sm[0];
}

// ---- LDS-tiled transpose: dst[m][c][r] = src[m][r][c]; R,C multiples of 32 ----
__global__ void k_tr(const float* src, float* dst, int R, int C){
  __shared__ float t[32][33];
  int m = blockIdx.z;
  const float* S = src + (size_t)m*R*C;
  float* Dp = dst + (size_t)m*R*C;
  int c0 = blockIdx.x*32, r0 = blockIdx.y*32;
  int tx = threadIdx.x & 31, ty = threadIdx.x >> 5;   // 8 rows per pass
  #pragma unroll
  for (int i=0;i<32;i+=8)
    t[ty+i][tx] = S[(size_t)(r0+ty+i)*C + c0+tx];
  __syncthreads();
  #pragma unroll
  for (int i=0;i<32;i+=8)
    Dp[(size_t)(c0+ty+i)*R + r0+tx] = t[tx][ty+i];
}

// ---- phiT[d][j] = phi_row(j)[d] * mhc_norm[k][d], tiled transpose ----
__global__ void k_phiT(P p){
  __shared__ float t[64][65];
  int jt = blockIdx.x % 18, dt = blockIdx.x / 18;
  int tx = threadIdx.x & 63, ty = threadIdx.x >> 6;   // 4 rows per pass
  #pragma unroll
  for (int i=0;i<64;i+=4){
    int j = jt*64 + ty + i;
    int k = j/24, r = j%24;
    const float* src;
    if (r < 4)      src = p.phi_pre  + (size_t)(k*4+r)*ND_;
    else if (r < 8) src = p.phi_post + (size_t)(k*4+(r-4))*ND_;
    else            src = p.phi_res  + (size_t)(k*16+(r-8))*ND_;
    int d = dt*64 + tx;
    t[ty+i][tx] = src[d] * p.mhc_norm[(size_t)k*ND_ + d];
  }
  __syncthreads();
  #pragma unroll
  for (int i=0;i<64;i+=4){
    int d = dt*64 + ty + i;
    p.phiT[(size_t)d*1152 + jt*64 + tx] = t[tx][ty+i];
  }
}

// ---- routing ----
__global__ void k_route(P p){
  int u = blockIdx.x, b = u>>9, t = u&511;
  __shared__ float ri[D_];
  __shared__ float lg[2][HE_];
  int tid = threadIdx.x;
  for (int d = tid; d < D_; d += 256){
    float s = 0;
    #pragma unroll
    for (int n = 0; n < N_; n++) s += p.stream[(((size_t)(b*N_+n)*T_)+t)*D_ + d];
    ri[d] = s * 0.25f;
  }
  __syncthreads();
  int lane = tid & 63, wv = tid >> 6;
  for (int j = wv; j < 2*HE_; j += 4){
    const float* w = (j < HE_ ? p.q_rw : p.kv_rw) + (size_t)(j % HE_)*D_;
    float acc = 0;
    for (int d = lane; d < D_; d += 64) acc += ri[d]*w[d];
    for (int off=32; off; off>>=1) acc += __shfl_down(acc, off, 64);
    if (lane==0) lg[j/HE_][j%HE_] = acc;
  }
  __syncthreads();
  if (tid < 16){
    int h = tid & 7, which = tid >> 3;
    const float* L = lg[which] + h*E_;
    float best = fminf(fmaxf(L[0],-10.f),10.f); int bi=0;
    for (int e=1;e<E_;e++){ float v=fminf(fmaxf(L[e],-10.f),10.f); if (v>best){best=v;bi=e;} }
    int g = h*E_+bi;
    if (which==0){ p.qsel[h*U_+u]=bi;  int pos=atomicAdd(&p.qcnt[g],1);  p.qlist[g*U_+pos]=u; }
    else         { p.kvsel[h*U_+u]=bi; int pos=atomicAdd(&p.kvcnt[g],1); p.kvlist[g*U_+pos]=u; }
  }
}

// ---- per-token rms scale of x (over ND) ----
__global__ void k_xscale(P p){
  int u = blockIdx.x, b = u>>9, t = u&511;
  __shared__ float sm[8];
  float ss = 0;
  for (int i = threadIdx.x; i < ND_; i += 256){
    int n = i >> 10, d = i & 1023;
    float v = p.stream[(((size_t)(b*N_+n)*T_)+t)*D_ + d];
    ss += v*v;
  }
  ss = block_reduce_sum(ss, sm);
  if (threadIdx.x==0) p.scale[u] = rsqrtf(ss/(float)ND_ + 1e-8f);
}

// ---- unified f32 tiled GEMM; MODE 0:mhc(K-split) 1:kv-wide 2:q 3:pg2 4:y ----
#define BM 128
#define BN 128
#define BK 32

template<int MODE>
__global__ __launch_bounds__(256) void k_gemm(P p){
  const int n0 = blockIdx.x * BN;
  const int m0 = blockIdx.y * BM;
  const int g  = blockIdx.z;          // expert (modes 1-3) or K-chunk (mode 0)
  const int h  = g / E_;
  int K, NO, cnt, kbase = 0;
  const int* list = nullptr;
  if (MODE==0){ K=1024; NO=1152; cnt=U_; kbase = g*1024; }
  else if (MODE==1){ K=D_;   NO=1194; cnt=p.kvcnt[g]; list=p.kvlist + g*U_; }
  else if (MODE==2){ K=D_;   NO=80;   cnt=p.qcnt[g];  list=p.qlist  + g*U_; }
  else if (MODE==3){ K=DPG_; NO=D_;   cnt=p.kvcnt[g]; list=p.kvlist + g*U_; }
  else { K=CC_; NO=D_; cnt=U_; }
  if (m0 >= cnt) return;
  const int rows = min(BM, cnt - m0);

  __shared__ __align__(16) float As[BK][BM+4];   // k-major A
  __shared__ __align__(16) float Bs[BK][BN+4];
  __shared__ int toks[BM];
  const int tid = threadIdx.x;
  for (int i = tid; i < BM; i += 256){
    if (MODE==1||MODE==2||MODE==3) toks[i] = (i < rows) ? list[m0+i] : 0;
    else toks[i] = m0 + i;
  }
  __syncthreads();

  float acc[8][8];
  #pragma unroll
  for (int i=0;i<8;i++){
    #pragma unroll
    for(int j=0;j<8;j++) acc[i][j]=0.f;
  }
  const int wave = tid >> 6, lane = tid & 63;
  const int wr = wave >> 1, wc = wave & 1;
  const int lr = lane >> 3, lc = lane & 7;
  const int a0 = wr*64 + lr*8, b0 = wc*64 + lc*8;

  for (int k0 = 0; k0 < K; k0 += BK){
    // stage A: BM x BK, global coalesced over k, LDS k-major
    #pragma unroll
    for (int i=0;i<16;i++){
      int idx = tid + 256*i;
      int r = idx >> 5, kk = idx & 31;
      int kg = k0 + kk;
      float v = 0.f;
      if (r < rows && kg < K){
        int u = toks[r];
        if (MODE==0){
          int kgg = kbase + kg;
          int b=u>>9, t=u&511, n=kgg>>10, d=kgg&1023;
          v = p.stream[(((size_t)(b*N_+n)*T_)+t)*D_ + d] * p.scale[u];
        } else if (MODE==1) v = p.he_kv[((size_t)(h*U_+u))*D_ + kg];
        else if (MODE==2)   v = p.he_q [((size_t)(h*U_+u))*D_ + kg];
        else if (MODE==3)   v = p.pg  [((size_t)(h*U_+u))*DPG_ + kg];
        else {
          size_t o = (size_t)u*CC_ + kg;
          v = p.attn[o] * sigm(p.pre_logit[o]);
        }
      }
      As[kk][r] = v;
    }
    // stage B: BK x BN, coalesced over columns
    #pragma unroll
    for (int i=0;i<16;i++){
      int idx = tid + 256*i;
      int kk = idx >> 7, c = idx & 127;
      int kg = k0 + kk, cg = n0 + c;
      float v = 0.f;
      if (kg < K && cg < NO){
        if (MODE==0) v = p.phiT[(size_t)(kbase+kg)*1152 + cg];
        else if (MODE==1){
          const float* ptr; int ld, loc;
          if (cg < 64){        ptr = p.WkT   + (size_t)h*D_*64;   ld=64;   loc=cg; }
          else if (cg < 128){  ptr = p.WvT   + (size_t)h*D_*64;   ld=64;   loc=cg-64; }
          else if (cg < 231){  ptr = p.a_up  + (size_t)g*D_*DA_;  ld=DA_;  loc=cg-128; }
          else if (cg < 334){  ptr = p.b_up  + (size_t)g*D_*DA_;  ld=DA_;  loc=cg-231; }
          else if (cg < 846){  ptr = p.W_pre + (size_t)g*D_*CC_;  ld=CC_;  loc=cg-334; }
          else if (cg < 1162){ ptr = p.W_pg1 + (size_t)g*D_*DPG_; ld=DPG_; loc=cg-846; }
          else if (cg < 1178){ ptr = p.lA_k  + (size_t)g*D_*R_;   ld=R_;   loc=cg-1162; }
          else {               ptr = p.lA_v  + (size_t)g*D_*R_;   ld=R_;   loc=cg-1178; }
          v = ptr[(size_t)kg*ld + loc];
        }
        else if (MODE==2){
          if (cg < 64) v = p.WqT[(size_t)h*D_*64 + (size_t)kg*64 + cg];
          else v = p.lA_q[(size_t)g*D_*R_ + (size_t)kg*R_ + (cg-64)];
        }
        else if (MODE==3) v = p.W_pg2[(size_t)g*DPG_*D_ + (size_t)kg*D_ + cg];
        else v = p.WoT[(size_t)kg*D_ + cg];
      }
      Bs[kk][c] = v;
    }
    __syncthreads();
    #pragma unroll 8
    for (int kk=0; kk<BK; kk++){
      float a[8], b[8];
      *(float4*)&a[0] = *(const float4*)&As[kk][a0];
      *(float4*)&a[4] = *(const float4*)&As[kk][a0+4];
      *(float4*)&b[0] = *(const float4*)&Bs[kk][b0];
      *(float4*)&b[4] = *(const float4*)&Bs[kk][b0+4];
      #pragma unroll
      for (int i=0;i<8;i++){
        #pragma unroll
        for (int j=0;j<8;j++) acc[i][j] += a[i]*b[j];
      }
    }
    __syncthreads();
  }

  #pragma unroll
  for (int i=0;i<8;i++){
    int rl = a0 + i;
    if (rl >= rows) continue;
    int u = toks[rl];
    #pragma unroll
    for (int j=0;j<8;j++){
      int cg = n0 + b0 + j;
      if (cg >= NO) continue;
      float v = acc[i][j];
      if (MODE==0){
        p.mhc_partial[(size_t)g*U_*1152 + (size_t)u*1152 + cg] = v;
      } else if (MODE==1){
        size_t base = (size_t)(h*U_+u);
        if (cg < 128)       p.kv_lin[base*128 + cg] = v;
        else if (cg < 231)  p.aup[base*DA_ + (cg-128)] = silu_(v);
        else if (cg < 334)  p.bup[base*DA_ + (cg-231)] = silu_(v);
        else if (cg < 846)  atomicAdd(&p.pre_logit[(size_t)u*CC_ + (cg-334)], v);
        else if (cg < 1162) p.pg[base*DPG_ + (cg-846)] = silu_(v);
        else if (cg < 1178) p.la_k[base*R_ + (cg-1162)] = silu_(v);
        else                p.la_v[base*R_ + (cg-1178)] = silu_(v);
      } else if (MODE==2){
        size_t base = (size_t)(h*U_+u);
        if (cg < 64) p.q_lin[base*64 + cg] = v;
        else         p.la_q[base*R_ + (cg-64)] = silu_(v);
      } else if (MODE==3){
        atomicAdd(&p.post_logit[(size_t)u*D_ + cg], v);
      } else {
        p.y[(size_t)u*D_ + cg] = v * sigm(p.post_logit[(size_t)u*D_ + cg]);
      }
    }
  }
}

// ---- selected-expert MHC gates + sinkhorn (sums 4 K-split partials) ----
DEV float lgread(const float* Pp, int j){
  const size_t S = (size_t)U_*1152;
  return Pp[j] + Pp[j+S] + Pp[j+2*S] + Pp[j+3*S];
}

__global__ void k_mhcsel(P p){
  int u = blockIdx.x;
  int tid = threadIdx.x;
  __shared__ float racc[8][16];
  __shared__ float pacc[8][4];
  if (tid < 8){
    int h = tid;
    const float* lg = p.mhc_partial + (size_t)u*1152;
    int kq = h*E_ + p.qsel[h*U_+u];
    for (int n=0;n<4;n++)
      p.Hpre_q[(size_t)(h*U_+u)*4 + n] = sigm(p.al_pre[kq]*lgread(lg,kq*24+n) + p.b_pre[kq*4+n]);
    int kk = h*E_ + p.kvsel[h*U_+u];
    for (int n=0;n<4;n++)
      p.Hpre_kv[(size_t)(h*U_+u)*4 + n] = sigm(p.al_pre[kk]*lgread(lg,kk*24+n) + p.b_pre[kk*4+n]);
    for (int n=0;n<4;n++)
      pacc[h][n] = 2.f*sigm(p.al_post[kk]*lgread(lg,kk*24+4+n) + p.b_post[kk*4+n]);
    float M[4][4];
    for (int n=0;n<4;n++)
      for (int m=0;m<4;m++)
        M[n][m] = expf(p.al_res[kk]*lgread(lg,kk*24+8+n*4+m) + p.b_res[kk*16+n*4+m]);
    for (int it=0; it<6; it++){
      for (int n=0;n<4;n++){ float s=M[n][0]+M[n][1]+M[n][2]+M[n][3]; float r=1.f/s;
        for(int m=0;m<4;m++) M[n][m]*=r; }
      for (int m=0;m<4;m++){ float s=M[0][m]+M[1][m]+M[2][m]+M[3][m]; float r=1.f/s;
        for(int n=0;n<4;n++) M[n][m]*=r; }
    }
    for (int n=0;n<4;n++) for (int m=0;m<4;m++) racc[h][n*4+m] = M[n][m];
  }
  __syncthreads();
  if (tid < 16){
    float s=0; for (int h=0;h<8;h++) s += racc[h][tid];
    p.Hres[(size_t)u*16 + tid] = s * 0.125f;
  }
  if (tid < 4){
    float s=0; for (int h=0;h<8;h++) s += pacc[h][tid];
    p.Hpost[(size_t)u*4 + tid] = s * 0.125f;
  }
}

// ---- h_e rows (selected experts only): path0=q, path1=kv ----
__global__ void k_he(P p){
  int id = blockIdx.x;
  int path = id >> 13;
  int h = (id >> 10) & 7;
  int u = id & 1023;
  int b = u>>9, t = u&511;
  int sel = path ? p.kvsel[h*U_+u] : p.qsel[h*U_+u];
  int k = h*E_ + sel;
  const float* Hp = (path ? p.Hpre_kv : p.Hpre_q) + (size_t)(h*U_+u)*4;
  float w0=Hp[0], w1=Hp[1], w2=Hp[2], w3=Hp[3];
  float v[4];
  float ss = 0;
  int tid = threadIdx.x;
  #pragma unroll
  for (int j=0;j<4;j++){
    int d = tid + j*256;
    float s0 = p.stream[(((size_t)(b*N_+0)*T_)+t)*D_ + d];
    float s1 = p.stream[(((size_t)(b*N_+1)*T_)+t)*D_ + d];
    float s2 = p.stream[(((size_t)(b*N_+2)*T_)+t)*D_ + d];
    float s3 = p.stream[(((size_t)(b*N_+3)*T_)+t)*D_ + d];
    v[j] = w0*s0 + w1*s1 + w2*s2 + w3*s3;
    ss += v[j]*v[j];
  }
  __shared__ float sm[8];
  ss = block_reduce_sum(ss, sm);
  float sc = rsqrtf(ss/(float)D_ + 1e-8f);
  float* out = (path ? p.he_kv : p.he_q) + (size_t)(h*U_+u)*D_;
  #pragma unroll
  for (int j=0;j<4;j++){
    int d = tid + j*256;
    out[d] = v[j]*sc*p.bn_w[(size_t)k*D_ + d];
  }
}

// ---- kv second stage ----
__global__ void k_stage2(P p){
  int id = blockIdx.x;
  int h = id >> 10, u = id & 1023;
  int t = u & 511;
  int k = h*E_ + p.kvsel[h*U_+u];
  size_t base = (size_t)(h*U_+u);
  __shared__ float s_au[DA_], s_bu[DA_], s_lk[R_], s_lv[R_], s_kl[64], s_vl[64];
  int tid = threadIdx.x;
  if (tid < DA_){ s_au[tid] = p.aup[base*DA_+tid]; s_bu[tid] = p.bup[base*DA_+tid]; }
  if (tid < R_){ s_lk[tid] = p.la_k[base*R_+tid]; s_lv[tid] = p.la_v[base*R_+tid]; }
  if (tid >= 64 && tid < 128){
    s_kl[tid-64] = p.kv_lin[base*128 + (tid-64)];
    s_vl[tid-64] = p.kv_lin[base*128 + 64 + (tid-64)];
  }
  __syncthreads();
  {
    float acc = 0;
    const float* W = p.a_dn + (size_t)k*DA_*DKP_;
    for (int a=0;a<DA_;a++) acc += s_au[a]*W[a*DKP_ + tid];
    p.a_buf[base*DKP_ + tid] = sigm(acc);
  }
  if (tid == 0){
    float acc = 0;
    const float* W = p.b_dn + (size_t)k*DA_;
    for (int a=0;a<DA_;a++) acc += s_bu[a]*W[a];
    p.b_buf[base] = sigm(acc);
  }
  if (tid < 64){
    int o = tid;
    float lbk=0.f, lbv=0.f;
    for (int r=0;r<R_;r++){
      lbk += s_lk[r]*p.lB_k[((size_t)k*R_+r)*DK_ + o];
      lbv += s_lv[r]*p.lB_v[((size_t)k*R_+r)*DV_ + o];
    }
    float kl = s_kl[o] + lbk;
    float ss = kl*kl;
    for (int off=1; off<64; off<<=1) ss += __shfl_xor(ss, off, 64);
    float kp = kl * rsqrtf(ss + 1e-12f);
    float mu = softplus_(kp);
    float ph = (float)t * p.freqs[o] - 6.2831855f * sigm(p.pope_delta[o]);
    p.k_buf[base*DKP_ + o]      = mu * cosf(ph);
    p.k_buf[base*DKP_ + 64 + o] = mu * sinf(ph);
    p.v_buf[base*DV_ + o] = s_vl[o] + lbv;
  }
}

// ---- q second stage ----
__global__ void k_stage2q(P p){
  int id = blockIdx.x;
  int h = id >> 10, u = id & 1023;
  int t = u & 511;
  int sel = p.qsel[h*U_+u];
  size_t base = (size_t)(h*U_+u);
  int o = threadIdx.x;
  if (sel == 0){
    p.q_buf[base*DKP_ + o] = 0.f;
    p.q_buf[base*DKP_ + 64 + o] = 0.f;
    return;
  }
  int k = h*E_ + sel;
  float lbq = 0.f;
  for (int r=0;r<R_;r++) lbq += p.la_q[base*R_+r]*p.lB_q[((size_t)k*R_+r)*DK_+o];
  float ql = p.q_lin[base*64 + o] + lbq;
  float ss = ql*ql;
  for (int off=1; off<64; off<<=1) ss += __shfl_xor(ss, off, 64);
  float qp = ql*rsqrtf(ss + 1e-12f);
  float mu = softplus_(qp);
  float ph = (float)t * p.freqs[o];
  p.q_buf[base*DKP_ + o]      = mu*cosf(ph);
  p.q_buf[base*DKP_ + 64 + o] = mu*sinf(ph);
}

// ---- KDA delta-rule scan ----
__global__ __launch_bounds__(512) void k_scan(P p){
  int h = blockIdx.x >> 1, b = blockIdx.x & 1;
  int tid = threadIdx.x;
  int e = tid & 63, d8 = tid >> 6;
  float S[16];
  #pragma unroll
  for (int i=0;i<16;i++) S[i]=0.f;
  __shared__ float sq[128], sk[128], sa[128], sv[64];
  __shared__ float sb;
  __shared__ float part[8][64];
  __shared__ float wshr[64];
  for (int t=0;t<T_;t++){
    int u = b*T_ + t;
    size_t base = (size_t)(h*U_+u);
    if (tid < 128){ sq[tid] = p.q_buf[base*128+tid]; sk[tid] = p.k_buf[base*128+tid]; }
    else if (tid < 256){ sa[tid-128] = p.a_buf[base*128 + (tid-128)]; }
    else if (tid < 320){ sv[tid-256] = p.v_buf[base*64 + (tid-256)]; }
    else if (tid == 320){ sb = p.b_buf[base]; }
    __syncthreads();
    float pa = 0.f;
    int db = d8*16;
    #pragma unroll
    for (int i=0;i<16;i++) pa += sk[db+i]*sa[db+i]*S[i];
    part[d8][e] = pa;
    __syncthreads();
    if (tid < 64){
      float s = 0;
      #pragma unroll
      for (int j=0;j<8;j++) s += part[j][tid];
      wshr[tid] = sv[tid] - s;
    }
    __syncthreads();
    float w = wshr[e], bs = sb;
    float o = 0.f;
    #pragma unroll
    for (int i=0;i<16;i++){
      S[i] = sa[db+i]*S[i] + bs*sk[db+i]*w;
      o += sq[db+i]*S[i];
    }
    part[d8][e] = o;
    __syncthreads();
    if (tid < 64){
      float s=0;
      #pragma unroll
      for (int j=0;j<8;j++) s += part[j][tid];
      p.attn[(size_t)u*CC_ + h*64 + tid] = s;
    }
  }
}

// ---- final ----
__global__ void k_final(P p){
  int u = blockIdx.x, b=u>>9, t=u&511;
  __shared__ float hr[16], hp[4];
  if (threadIdx.x < 16) hr[threadIdx.x] = p.Hres[(size_t)u*16+threadIdx.x];
  if (threadIdx.x < 4)  hp[threadIdx.x] = p.Hpost[(size_t)u*4+threadIdx.x];
  __syncthreads();
  for (int d = threadIdx.x; d < D_; d += 256){
    float yv = p.y[(size_t)u*D_ + d];
    float sm0 = p.stream[(((size_t)(b*N_+0)*T_)+t)*D_ + d];
    float sm1 = p.stream[(((size_t)(b*N_+1)*T_)+t)*D_ + d];
    float sm2 = p.stream[(((size_t)(b*N_+2)*T_)+t)*D_ + d];
    float sm3 = p.stream[(((size_t)(b*N_+3)*T_)+t)*D_ + d];
    #pragma unroll
    for (int n=0;n<4;n++){
      float v = hr[n*4+0]*sm0 + hr[n*4+1]*sm1 + hr[n*4+2]*sm2 + hr[n*4+3]*sm3 + hp[n]*yv;
      p.out[(((size_t)(b*N_+n)*T_)+t)*D_ + d] = v;
    }
  }
}

extern "C" void kernel_launch(void* const* d_in, const int* in_sizes, int n_in,
                              void* d_out, int out_size, void* d_ws, size_t ws_size,
                              hipStream_t stream){
  P p;
  p.stream = (const float*)d_in[0];
  p.freqs = (const float*)d_in[1];
  p.pope_delta = (const float*)d_in[2];
  p.W_q = (const float*)d_in[3]; p.W_k = (const float*)d_in[4]; p.W_v = (const float*)d_in[5];
  p.q_rw = (const float*)d_in[6]; p.kv_rw = (const float*)d_in[7];
  p.lA_q = (const float*)d_in[8];  p.lB_q = (const float*)d_in[9];
  p.lA_k = (const float*)d_in[10]; p.lB_k = (const float*)d_in[11];
  p.lA_v = (const float*)d_in[12]; p.lB_v = (const float*)d_in[13];
  p.a_up = (const float*)d_in[14]; p.a_dn = (const float*)d_in[15];
  p.b_up = (const float*)d_in[16]; p.b_dn = (const float*)d_in[17];
  p.mhc_norm = (const float*)d_in[18];
  p.phi_pre = (const float*)d_in[19]; p.phi_post = (const float*)d_in[20]; p.phi_res = (const float*)d_in[21];
  p.b_pre = (const float*)d_in[22]; p.b_post = (const float*)d_in[23]; p.b_res = (const float*)d_in[24];
  p.al_pre = (const float*)d_in[25]; p.al_post = (const float*)d_in[26]; p.al_res = (const float*)d_in[27];
  p.bn_w = (const float*)d_in[28];
  p.W_pre = (const float*)d_in[29]; p.W_o = (const float*)d_in[30];
  p.W_pg1 = (const float*)d_in[31]; p.W_pg2 = (const float*)d_in[32];
  p.out = (float*)d_out;

  char* w = (char*)d_ws;
  size_t off = 0;
  auto alloc = [&](size_t bytes)->void*{
    void* r = w + off;
    off = (off + bytes + 255) & ~(size_t)255;
    return r;
  };
  p.qsel   = (int*)alloc(H_*U_*4);
  p.kvsel  = (int*)alloc(H_*U_*4);
  p.qcnt   = (int*)alloc(HE_*4);
  p.kvcnt  = (int*)alloc(HE_*4);
  p.qlist  = (int*)alloc(HE_*U_*4);
  p.kvlist = (int*)alloc(HE_*U_*4);
  p.scale  = (float*)alloc(U_*4);
  p.phiT   = (float*)alloc((size_t)ND_*1152*4);
  p.mhc_partial = (float*)alloc((size_t)4*U_*1152*4);
  p.Hpre_q  = (float*)alloc((size_t)H_*U_*4*4);
  p.Hpre_kv = (float*)alloc((size_t)H_*U_*4*4);
  p.Hres    = (float*)alloc((size_t)U_*16*4);
  p.Hpost   = (float*)alloc((size_t)U_*4*4);
  p.he_kv   = (float*)alloc((size_t)H_*U_*D_*4);
  p.he_q    = (float*)alloc((size_t)H_*U_*D_*4);
  p.WqT     = (float*)alloc((size_t)H_*D_*64*4);
  p.WkT     = (float*)alloc((size_t)H_*D_*64*4);
  p.WvT     = (float*)alloc((size_t)H_*D_*64*4);
  p.WoT     = (float*)alloc((size_t)CC_*D_*4);
  p.kv_lin  = (float*)alloc((size_t)H_*U_*128*4);
  p.aup     = (float*)alloc((size_t)H_*U_*DA_*4);
  p.bup     = (float*)alloc((size_t)H_*U_*DA_*4);
  p.pre_logit  = (float*)alloc((size_t)U_*CC_*4);
  p.pg         = (float*)alloc((size_t)H_*U_*DPG_*4);
  p.post_logit = (float*)alloc((size_t)U_*D_*4);
  p.la_k    = (float*)alloc((size_t)H_*U_*R_*4);
  p.la_v    = (float*)alloc((size_t)H_*U_*R_*4);
  p.la_q    = (float*)alloc((size_t)H_*U_*R_*4);
  p.q_lin   = (float*)alloc((size_t)H_*U_*64*4);
  p.a_buf   = (float*)alloc((size_t)H_*U_*DKP_*4);
  p.b_buf   = (float*)alloc((size_t)H_*U_*4);
  p.q_buf   = (float*)alloc((size_t)H_*U_*DKP_*4);
  p.k_buf   = (float*)alloc((size_t)H_*U_*DKP_*4);
  p.v_buf   = (float*)alloc((size_t)H_*U_*DV_*4);
  p.attn    = (float*)alloc((size_t)U_*CC_*4);
  p.y       = (float*)alloc((size_t)U_*D_*4);
  if (off > ws_size) return;

  hipMemsetAsync(p.qcnt, 0, HE_*4, stream);
  hipMemsetAsync(p.kvcnt, 0, HE_*4, stream);
  hipMemsetAsync(p.pre_logit, 0, (size_t)U_*CC_*4, stream);
  hipMemsetAsync(p.post_logit, 0, (size_t)U_*D_*4, stream);

  k_tr<<<dim3(32,2,8),256,0,stream>>>(p.W_q, p.WqT, 64, 1024);
  k_tr<<<dim3(32,2,8),256,0,stream>>>(p.W_k, p.WkT, 64, 1024);
  k_tr<<<dim3(32,2,8),256,0,stream>>>(p.W_v, p.WvT, 64, 1024);
  k_tr<<<dim3(16,32,1),256,0,stream>>>(p.W_o, p.WoT, 1024, 512);
  k_phiT<<<1152,256,0,stream>>>(p);
  k_route<<<U_,256,0,stream>>>(p);
  k_xscale<<<U_,256,0,stream>>>(p);
  k_gemm<0><<<dim3(9,8,4),256,0,stream>>>(p);
  k_mhcsel<<<U_,64,0,stream>>>(p);
  k_he<<<2*H_*U_,256,0,stream>>>(p);
  k_gemm<1><<<dim3(10,8,48),256,0,stream>>>(p);
  k_gemm<2><<<dim3(1,8,48),256,0,stream>>>(p);
  k_stage2<<<H_*U_,128,0,stream>>>(p);
  k_stage2q<<<H_*U_,64,0,stream>>>(p);
  k_gemm<3><<<dim3(8,8,48),256,0,stream>>>(p);
  k_scan<<<16,512,0,stream>>>(p);
  k_gemm<4><<<dim3(8,8,1),256,0,stream>>>(p);
  k_final<<<U_,256,0,stream>>>(p);
}

// Round 3
// 1536.545 us; speedup vs baseline: 2.3670x; 2.3670x over previous
//
#include <hip/hip_runtime.h>
#include <math.h>

#define DEV static __device__ __forceinline__

// ---- problem constants ----
#define B_   2
#define N_   4
#define T_   512
#define D_   1024
#define DK_  64
#define H_   8
#define E_   6
#define DV_  64
#define DKP_ 128
#define HE_  48
#define R_   16
#define DA_  103
#define CC_  512
#define DPG_ 316
#define ND_  4096
#define U_   1024      // B*T tokens

typedef unsigned short u16;
typedef __attribute__((ext_vector_type(8))) unsigned short us8;
typedef __attribute__((ext_vector_type(8))) short bhalf8;
typedef __attribute__((ext_vector_type(4))) float f32x4;

struct P {
  // inputs
  const float *stream, *freqs, *pope_delta;
  const float *W_q, *W_k, *W_v, *q_rw, *kv_rw;
  const float *lA_q, *lB_q, *lA_k, *lB_k, *lA_v, *lB_v;
  const float *a_up, *a_dn, *b_up, *b_dn;
  const float *mhc_norm, *phi_pre, *phi_post, *phi_res;
  const float *b_pre, *b_post, *b_res, *al_pre, *al_post, *al_res;
  const float *bn_w, *W_pre, *W_o, *W_pg1, *W_pg2;
  // workspace (shared)
  int *qsel, *kvsel, *qcnt, *kvcnt, *qlist, *kvlist;
  float *scale, *mhc_partial;
  float *Hpre_q, *Hpre_kv, *Hres, *Hpost;
  float *kv_lin, *aup, *bup, *pre_logit, *post_logit;
  float *la_k, *la_v, *la_q, *q_lin;
  float *a_buf, *b_buf, *q_buf, *k_buf, *v_buf;
  float *attn, *y;
  float *out;
  // mfma path
  u16 *he_kvB, *he_qB, *pgB;
  u16 *Bt0, *Bt1, *Bt2, *Bt3, *Bt4;
  // f32 fallback path
  float *phiT, *he_kvF, *he_qF, *pgF;
  float *WqT, *WkT, *WvT, *WoT;
};

DEV float sigm(float x){ return 1.f/(1.f+expf(-x)); }
DEV float softplus_(float x){ return x>0.f ? x+log1pf(expf(-x)) : log1pf(expf(x)); }
DEV float silu_(float x){ return x*sigm(x); }
DEV u16 f2b(float x){ unsigned u = __float_as_uint(x); u += 0x7FFFu + ((u>>16)&1u); return (u16)(u>>16); }

DEV float block_reduce_sum(float v, float* sm){
  __syncthreads();
  int lane = threadIdx.x & 63, w = threadIdx.x >> 6;
  for (int off=32; off; off>>=1) v += __shfl_down(v, off, 64);
  if (lane==0) sm[w] = v;
  __syncthreads();
  if (threadIdx.x == 0){
    float s = 0; int nw = blockDim.x >> 6;
    for (int i=0;i<nw;i++) s += sm[i];
    sm[0] = s;
  }
  __syncthreads();
  return sm[0];
}

// ============================ prep kernels (bf16 B panels) ============================

// Bt0[j][0..4095] = phi_row_j * mhc_norm
__global__ void k_prep0(P p){
  int j = blockIdx.x; int k = j/24, r = j%24;
  const float* src;
  if (r < 4)      src = p.phi_pre  + (size_t)(k*4+r)*ND_;
  else if (r < 8) src = p.phi_post + (size_t)(k*4+(r-4))*ND_;
  else            src = p.phi_res  + (size_t)(k*16+(r-8))*ND_;
  const float* mn = p.mhc_norm + (size_t)k*ND_;
  u16* d = p.Bt0 + (size_t)j*ND_;
  for (int i = threadIdx.x; i < ND_; i += 256) d[i] = f2b(src[i]*mn[i]);
}

// Bt1 direct rows: 0..63 W_k[h], 64..127 W_v[h], rows 1194..1215 zero
__global__ void k_prep1d(P p){
  int r = blockIdx.x, g = blockIdx.y, h = g/E_;
  u16* drow = p.Bt1 + (size_t)g*1216*1024 + (size_t)(r<128 ? r : 1194 + (r-128))*1024;
  const float* srow = (r<64) ? (p.W_k + ((size_t)h*64 + r)*1024)
                   : (r<128) ? (p.W_v + ((size_t)h*64 + (r-64))*1024) : nullptr;
  for (int k2 = threadIdx.x; k2 < 1024; k2 += 256)
    drow[k2] = (r<128) ? f2b(srow[k2]) : (u16)0;
}

// Bt2 direct rows 0..63 = W_q[h]
__global__ void k_prep2d(P p){
  int r = blockIdx.x, g = blockIdx.y, h = g/E_;
  u16* drow = p.Bt2 + (size_t)g*128*1024 + (size_t)r*1024;
  const float* srow = p.W_q + ((size_t)h*64 + r)*1024;
  for (int k2 = threadIdx.x; k2 < 1024; k2 += 256) drow[k2] = f2b(srow[k2]);
}

// Bt4 = W_o direct
__global__ void k_prep4(P p){
  int r = blockIdx.x;
  u16* drow = p.Bt4 + (size_t)r*512;
  const float* srow = p.W_o + (size_t)r*512;
  for (int c = threadIdx.x; c < 512; c += 256) drow[c] = f2b(srow[c]);
}

// generic tiled transpose+cvt: dst[c][k] = src[k*ld + c]
__global__ void k_prept(const float* src, long sstride, int ld, int ncols,
                        u16* dst, long dstride, int dld, int K, int Ksrc){
  __shared__ float t[32][33];
  const float* S = src + (size_t)blockIdx.z*sstride;
  u16* Dp = dst + (size_t)blockIdx.z*dstride;
  int k0 = blockIdx.x*32, c0 = blockIdx.y*32;
  int tx = threadIdx.x & 31, ty = threadIdx.x >> 5;
  #pragma unroll
  for (int i=0;i<32;i+=8){
    int k = k0+ty+i, c = c0+tx;
    t[ty+i][tx] = (k < Ksrc && c < ncols) ? S[(size_t)k*ld + c] : 0.f;
  }
  __syncthreads();
  #pragma unroll
  for (int i=0;i<32;i+=8){
    int c = c0+ty+i, k = k0+tx;
    if (c < ncols && k < K) Dp[(size_t)c*dld + k] = f2b(t[tx][ty+i]);
  }
}

// ============================ routing / norms ============================

__global__ void k_route(P p){
  int u = blockIdx.x, b = u>>9, t = u&511;
  __shared__ float ri[D_];
  __shared__ float lg[2][HE_];
  int tid = threadIdx.x;
  for (int d = tid; d < D_; d += 256){
    float s = 0;
    #pragma unroll
    for (int n = 0; n < N_; n++) s += p.stream[(((size_t)(b*N_+n)*T_)+t)*D_ + d];
    ri[d] = s * 0.25f;
  }
  __syncthreads();
  int lane = tid & 63, wv = tid >> 6;
  for (int j = wv; j < 2*HE_; j += 4){
    const float* w = (j < HE_ ? p.q_rw : p.kv_rw) + (size_t)(j % HE_)*D_;
    float acc = 0;
    for (int d = lane; d < D_; d += 64) acc += ri[d]*w[d];
    for (int off=32; off; off>>=1) acc += __shfl_down(acc, off, 64);
    if (lane==0) lg[j/HE_][j%HE_] = acc;
  }
  __syncthreads();
  if (tid < 16){
    int h = tid & 7, which = tid >> 3;
    const float* L = lg[which] + h*E_;
    float best = fminf(fmaxf(L[0],-10.f),10.f); int bi=0;
    for (int e=1;e<E_;e++){ float v=fminf(fmaxf(L[e],-10.f),10.f); if (v>best){best=v;bi=e;} }
    int g = h*E_+bi;
    if (which==0){ p.qsel[h*U_+u]=bi;  int pos=atomicAdd(&p.qcnt[g],1);  p.qlist[g*U_+pos]=u; }
    else         { p.kvsel[h*U_+u]=bi; int pos=atomicAdd(&p.kvcnt[g],1); p.kvlist[g*U_+pos]=u; }
  }
}

__global__ void k_xscale(P p){
  int u = blockIdx.x, b = u>>9, t = u&511;
  __shared__ float sm[8];
  float ss = 0;
  for (int i = threadIdx.x; i < ND_; i += 256){
    int n = i >> 10, d = i & 1023;
    float v = p.stream[(((size_t)(b*N_+n)*T_)+t)*D_ + d];
    ss += v*v;
  }
  ss = block_reduce_sum(ss, sm);
  if (threadIdx.x==0) p.scale[u] = rsqrtf(ss/(float)ND_ + 1e-8f);
}

// ============================ MFMA GEMM (bf16 in, f32 acc) ============================
// MODE 0: mhc logits (K-chunked, partials)  1: kv-wide  2: q  3: pg2  4: y

template<int MODE>
__global__ __launch_bounds__(256) void k_mgemm(P p){
  const int n0 = blockIdx.x * 128;
  const int m0 = blockIdx.y * 128;
  const int g  = blockIdx.z;
  const int h  = g / E_;
  int K, NO, cnt;
  const int* list = nullptr;
  const u16* Bsrc;
  if (MODE==0){ K=1024; NO=1152; cnt=U_; Bsrc=p.Bt0; }
  else if (MODE==1){ K=1024; NO=1194; cnt=p.kvcnt[g]; list=p.kvlist+g*U_; Bsrc=p.Bt1+(size_t)g*1216*1024; }
  else if (MODE==2){ K=1024; NO=80;   cnt=p.qcnt[g];  list=p.qlist +g*U_; Bsrc=p.Bt2+(size_t)g*128*1024; }
  else if (MODE==3){ K=320;  NO=1024; cnt=p.kvcnt[g]; list=p.kvlist+g*U_; Bsrc=p.Bt3+(size_t)g*1024*320; }
  else { K=512; NO=1024; cnt=U_; Bsrc=p.Bt4; }
  if (m0 >= cnt) return;
  const int rows = min(128, cnt - m0);

  __shared__ u16 Asl[128*32];
  __shared__ u16 Bsl[128*32];
  __shared__ int toks[128];
  const int tid = threadIdx.x;
  if (tid < 128){
    if (MODE==0||MODE==4) toks[tid] = m0 + tid;
    else toks[tid] = (tid < rows) ? list[m0+tid] : list[m0];
  }
  __syncthreads();

  f32x4 acc[4][4];
  #pragma unroll
  for (int i=0;i<4;i++)
    #pragma unroll
    for (int j=0;j<4;j++) acc[i][j] = (f32x4)(0.f);

  const int lane = tid & 63, wv = tid >> 6;
  const int wr = (wv>>1)*64, wc = (wv&1)*64;
  const int l16 = lane & 15, kce = lane >> 4;

  for (int k0 = 0; k0 < K; k0 += 32){
    // ---- stage A (128 rows x 32 k) ----
    #pragma unroll
    for (int pass=0; pass<2; pass++){
      int m = (tid>>2) + pass*64;
      int kc4 = tid & 3;
      int ks = k0 + kc4*8;
      us8 av;
      if (MODE==1){
        int u = toks[m];
        av = *(const us8*)&p.he_kvB[((size_t)(h*U_+u))*1024 + ks];
      } else if (MODE==2){
        int u = toks[m];
        av = *(const us8*)&p.he_qB[((size_t)(h*U_+u))*1024 + ks];
      } else if (MODE==3){
        int u = toks[m];
        av = *(const us8*)&p.pgB[((size_t)(h*U_+u))*320 + ks];
      } else if (MODE==0){
        int u = toks[m]; int bb=u>>9, tt=u&511;
        int fk = g*1024 + ks;
        int n = fk>>10, d = fk&1023;
        const float* sp = p.stream + (((size_t)(bb*N_+n)*T_)+tt)*D_ + d;
        float sc = p.scale[u];
        float4 x0 = *(const float4*)sp, x1 = *(const float4*)(sp+4);
        av[0]=f2b(x0.x*sc); av[1]=f2b(x0.y*sc); av[2]=f2b(x0.z*sc); av[3]=f2b(x0.w*sc);
        av[4]=f2b(x1.x*sc); av[5]=f2b(x1.y*sc); av[6]=f2b(x1.z*sc); av[7]=f2b(x1.w*sc);
      } else {
        int u = toks[m];
        const float* ap = p.attn + (size_t)u*CC_ + ks;
        const float* pp = p.pre_logit + (size_t)u*CC_ + ks;
        float4 a0 = *(const float4*)ap, a1 = *(const float4*)(ap+4);
        float4 q0 = *(const float4*)pp, q1 = *(const float4*)(pp+4);
        av[0]=f2b(a0.x*sigm(q0.x)); av[1]=f2b(a0.y*sigm(q0.y));
        av[2]=f2b(a0.z*sigm(q0.z)); av[3]=f2b(a0.w*sigm(q0.w));
        av[4]=f2b(a1.x*sigm(q1.x)); av[5]=f2b(a1.y*sigm(q1.y));
        av[6]=f2b(a1.z*sigm(q1.z)); av[7]=f2b(a1.w*sigm(q1.w));
      }
      *(us8*)&Asl[m*32 + kc4*8] = av;
    }
    // ---- stage B (128 cols x 32 k) ----
    #pragma unroll
    for (int pass=0; pass<2; pass++){
      int n = (tid>>2) + pass*64;
      int kc4 = tid & 3;
      int ks = k0 + kc4*8;
      int gn = n0 + n;
      us8 bv = (us8)((u16)0);
      if (MODE==1){ if (gn < 1216) bv = *(const us8*)&Bsrc[(size_t)gn*1024 + ks]; }
      else if (MODE==0){ bv = *(const us8*)&Bsrc[(size_t)gn*4096 + g*1024 + ks]; }
      else if (MODE==2){ bv = *(const us8*)&Bsrc[(size_t)gn*1024 + ks]; }
      else if (MODE==3){ bv = *(const us8*)&Bsrc[(size_t)gn*320 + ks]; }
      else { bv = *(const us8*)&Bsrc[(size_t)gn*512 + ks]; }
      *(us8*)&Bsl[n*32 + kc4*8] = bv;
    }
    __syncthreads();
    // ---- MFMA ----
    bhalf8 af[4], bf4[4];
    #pragma unroll
    for (int i=0;i<4;i++) af[i] = *(const bhalf8*)&Asl[(wr + i*16 + l16)*32 + kce*8];
    #pragma unroll
    for (int j=0;j<4;j++) bf4[j] = *(const bhalf8*)&Bsl[(wc + j*16 + l16)*32 + kce*8];
    #pragma unroll
    for (int i=0;i<4;i++)
      #pragma unroll
      for (int j=0;j<4;j++)
        acc[i][j] = __builtin_amdgcn_mfma_f32_16x16x32_bf16(af[i], bf4[j], acc[i][j], 0, 0, 0);
    __syncthreads();
  }

  // ---- epilogue: C layout col=lane&15, row=(lane>>4)*4+reg ----
  #pragma unroll
  for (int i=0;i<4;i++){
    #pragma unroll
    for (int r=0;r<4;r++){
      int rl = wr + i*16 + kce*4 + r;
      if (rl >= rows) continue;
      int u = toks[rl];
      #pragma unroll
      for (int j=0;j<4;j++){
        int cg = n0 + wc + j*16 + l16;
        if (cg >= NO) continue;
        float v = acc[i][j][r];
        if (MODE==0){
          p.mhc_partial[(size_t)g*U_*1152 + (size_t)u*1152 + cg] = v;
        } else if (MODE==1){
          size_t base = (size_t)(h*U_+u);
          if (cg < 128)       p.kv_lin[base*128 + cg] = v;
          else if (cg < 231)  p.aup[base*DA_ + (cg-128)] = silu_(v);
          else if (cg < 334)  p.bup[base*DA_ + (cg-231)] = silu_(v);
          else if (cg < 846)  atomicAdd(&p.pre_logit[(size_t)u*CC_ + (cg-334)], v);
          else if (cg < 1162) p.pgB[base*320 + (cg-846)] = f2b(silu_(v));
          else if (cg < 1178) p.la_k[base*R_ + (cg-1162)] = silu_(v);
          else                p.la_v[base*R_ + (cg-1178)] = silu_(v);
        } else if (MODE==2){
          size_t base = (size_t)(h*U_+u);
          if (cg < 64) p.q_lin[base*64 + cg] = v;
          else         p.la_q[base*R_ + (cg-64)] = silu_(v);
        } else if (MODE==3){
          atomicAdd(&p.post_logit[(size_t)u*D_ + cg], v);
        } else {
          p.y[(size_t)u*D_ + cg] = v * sigm(p.post_logit[(size_t)u*D_ + cg]);
        }
      }
    }
  }
}

// ============================ f32 fallback GEMM (round-2, known-correct) ============================
#define BM 128
#define BN 128
#define BKF 32

template<int MODE>
__global__ __launch_bounds__(256) void k_gemm_f32(P p){
  const int n0 = blockIdx.x * BN;
  const int m0 = blockIdx.y * BM;
  const int g  = blockIdx.z;
  const int h  = g / E_;
  int K, NO, cnt, kbase = 0;
  const int* list = nullptr;
  if (MODE==0){ K=1024; NO=1152; cnt=U_; kbase = g*1024; }
  else if (MODE==1){ K=D_;   NO=1194; cnt=p.kvcnt[g]; list=p.kvlist + g*U_; }
  else if (MODE==2){ K=D_;   NO=80;   cnt=p.qcnt[g];  list=p.qlist  + g*U_; }
  else if (MODE==3){ K=DPG_; NO=D_;   cnt=p.kvcnt[g]; list=p.kvlist + g*U_; }
  else { K=CC_; NO=D_; cnt=U_; }
  if (m0 >= cnt) return;
  const int rows = min(BM, cnt - m0);

  __shared__ __align__(16) float As[BKF][BM+4];
  __shared__ __align__(16) float Bs[BKF][BN+4];
  __shared__ int toks[BM];
  const int tid = threadIdx.x;
  for (int i = tid; i < BM; i += 256){
    if (MODE==1||MODE==2||MODE==3) toks[i] = (i < rows) ? list[m0+i] : 0;
    else toks[i] = m0 + i;
  }
  __syncthreads();

  float acc[8][8];
  #pragma unroll
  for (int i=0;i<8;i++)
    #pragma unroll
    for(int j=0;j<8;j++) acc[i][j]=0.f;
  const int wave = tid >> 6, lane = tid & 63;
  const int wr = wave >> 1, wc = wave & 1;
  const int lr = lane >> 3, lc = lane & 7;
  const int a0 = wr*64 + lr*8, b0 = wc*64 + lc*8;

  for (int k0 = 0; k0 < K; k0 += BKF){
    #pragma unroll
    for (int i=0;i<16;i++){
      int idx = tid + 256*i;
      int r = idx >> 5, kk = idx & 31;
      int kg = k0 + kk;
      float v = 0.f;
      if (r < rows && kg < K){
        int u = toks[r];
        if (MODE==0){
          int kgg = kbase + kg;
          int b=u>>9, t=u&511, n=kgg>>10, d=kgg&1023;
          v = p.stream[(((size_t)(b*N_+n)*T_)+t)*D_ + d] * p.scale[u];
        } else if (MODE==1) v = p.he_kvF[((size_t)(h*U_+u))*D_ + kg];
        else if (MODE==2)   v = p.he_qF [((size_t)(h*U_+u))*D_ + kg];
        else if (MODE==3)   v = p.pgF  [((size_t)(h*U_+u))*DPG_ + kg];
        else {
          size_t o = (size_t)u*CC_ + kg;
          v = p.attn[o] * sigm(p.pre_logit[o]);
        }
      }
      As[kk][r] = v;
    }
    #pragma unroll
    for (int i=0;i<16;i++){
      int idx = tid + 256*i;
      int kk = idx >> 7, c = idx & 127;
      int kg = k0 + kk, cg = n0 + c;
      float v = 0.f;
      if (kg < K && cg < NO){
        if (MODE==0) v = p.phiT[(size_t)(kbase+kg)*1152 + cg];
        else if (MODE==1){
          const float* ptr; int ld, loc;
          if (cg < 64){        ptr = p.WkT   + (size_t)h*D_*64;   ld=64;   loc=cg; }
          else if (cg < 128){  ptr = p.WvT   + (size_t)h*D_*64;   ld=64;   loc=cg-64; }
          else if (cg < 231){  ptr = p.a_up  + (size_t)g*D_*DA_;  ld=DA_;  loc=cg-128; }
          else if (cg < 334){  ptr = p.b_up  + (size_t)g*D_*DA_;  ld=DA_;  loc=cg-231; }
          else if (cg < 846){  ptr = p.W_pre + (size_t)g*D_*CC_;  ld=CC_;  loc=cg-334; }
          else if (cg < 1162){ ptr = p.W_pg1 + (size_t)g*D_*DPG_; ld=DPG_; loc=cg-846; }
          else if (cg < 1178){ ptr = p.lA_k  + (size_t)g*D_*R_;   ld=R_;   loc=cg-1162; }
          else {               ptr = p.lA_v  + (size_t)g*D_*R_;   ld=R_;   loc=cg-1178; }
          v = ptr[(size_t)kg*ld + loc];
        }
        else if (MODE==2){
          if (cg < 64) v = p.WqT[(size_t)h*D_*64 + (size_t)kg*64 + cg];
          else v = p.lA_q[(size_t)g*D_*R_ + (size_t)kg*R_ + (cg-64)];
        }
        else if (MODE==3) v = p.W_pg2[(size_t)g*DPG_*D_ + (size_t)kg*D_ + cg];
        else v = p.WoT[(size_t)kg*D_ + cg];
      }
      Bs[kk][c] = v;
    }
    __syncthreads();
    #pragma unroll 8
    for (int kk=0; kk<BKF; kk++){
      float a[8], b[8];
      *(float4*)&a[0] = *(const float4*)&As[kk][a0];
      *(float4*)&a[4] = *(const float4*)&As[kk][a0+4];
      *(float4*)&b[0] = *(const float4*)&Bs[kk][b0];
      *(float4*)&b[4] = *(const float4*)&Bs[kk][b0+4];
      #pragma unroll
      for (int i=0;i<8;i++)
        #pragma unroll
        for (int j=0;j<8;j++) acc[i][j] += a[i]*b[j];
    }
    __syncthreads();
  }

  #pragma unroll
  for (int i=0;i<8;i++){
    int rl = a0 + i;
    if (rl >= rows) continue;
    int u = toks[rl];
    #pragma unroll
    for (int j=0;j<8;j++){
      int cg = n0 + b0 + j;
      if (cg >= NO) continue;
      float v = acc[i][j];
      if (MODE==0){
        p.mhc_partial[(size_t)g*U_*1152 + (size_t)u*1152 + cg] = v;
      } else if (MODE==1){
        size_t base = (size_t)(h*U_+u);
        if (cg < 128)       p.kv_lin[base*128 + cg] = v;
        else if (cg < 231)  p.aup[base*DA_ + (cg-128)] = silu_(v);
        else if (cg < 334)  p.bup[base*DA_ + (cg-231)] = silu_(v);
        else if (cg < 846)  atomicAdd(&p.pre_logit[(size_t)u*CC_ + (cg-334)], v);
        else if (cg < 1162) p.pgF[base*DPG_ + (cg-846)] = silu_(v);
        else if (cg < 1178) p.la_k[base*R_ + (cg-1162)] = silu_(v);
        else                p.la_v[base*R_ + (cg-1178)] = silu_(v);
      } else if (MODE==2){
        size_t base = (size_t)(h*U_+u);
        if (cg < 64) p.q_lin[base*64 + cg] = v;
        else         p.la_q[base*R_ + (cg-64)] = silu_(v);
      } else if (MODE==3){
        atomicAdd(&p.post_logit[(size_t)u*D_ + cg], v);
      } else {
        p.y[(size_t)u*D_ + cg] = v * sigm(p.post_logit[(size_t)u*D_ + cg]);
      }
    }
  }
}

// ---- fallback helpers ----
__global__ void k_tr(const float* src, float* dst, int R, int C){
  __shared__ float t[32][33];
  int m = blockIdx.z;
  const float* S = src + (size_t)m*R*C;
  float* Dp = dst + (size_t)m*R*C;
  int c0 = blockIdx.x*32, r0 = blockIdx.y*32;
  int tx = threadIdx.x & 31, ty = threadIdx.x >> 5;
  #pragma unroll
  for (int i=0;i<32;i+=8)
    t[ty+i][tx] = S[(size_t)(r0+ty+i)*C + c0+tx];
  __syncthreads();
  #pragma unroll
  for (int i=0;i<32;i+=8)
    Dp[(size_t)(c0+ty+i)*R + r0+tx] = t[tx][ty+i];
}

__global__ void k_phiT(P p){
  __shared__ float t[64][65];
  int jt = blockIdx.x % 18, dt = blockIdx.x / 18;
  int tx = threadIdx.x & 63, ty = threadIdx.x >> 6;
  #pragma unroll
  for (int i=0;i<64;i+=4){
    int j = jt*64 + ty + i;
    int k = j/24, r = j%24;
    const float* src;
    if (r < 4)      src = p.phi_pre  + (size_t)(k*4+r)*ND_;
    else if (r < 8) src = p.phi_post + (size_t)(k*4+(r-4))*ND_;
    else            src = p.phi_res  + (size_t)(k*16+(r-8))*ND_;
    int d = dt*64 + tx;
    t[ty+i][tx] = src[d] * p.mhc_norm[(size_t)k*ND_ + d];
  }
  __syncthreads();
  #pragma unroll
  for (int i=0;i<64;i+=4){
    int d = dt*64 + ty + i;
    p.phiT[(size_t)d*1152 + jt*64 + tx] = t[tx][ty+i];
  }
}

// ============================ shared downstream kernels ============================

DEV float lgread(const float* Pp, int j){
  const size_t S = (size_t)U_*1152;
  return Pp[j] + Pp[j+S] + Pp[j+2*S] + Pp[j+3*S];
}

__global__ void k_mhcsel(P p){
  int u = blockIdx.x;
  int tid = threadIdx.x;
  __shared__ float racc[8][16];
  __shared__ float pacc[8][4];
  if (tid < 8){
    int h = tid;
    const float* lg = p.mhc_partial + (size_t)u*1152;
    int kq = h*E_ + p.qsel[h*U_+u];
    for (int n=0;n<4;n++)
      p.Hpre_q[(size_t)(h*U_+u)*4 + n] = sigm(p.al_pre[kq]*lgread(lg,kq*24+n) + p.b_pre[kq*4+n]);
    int kk = h*E_ + p.kvsel[h*U_+u];
    for (int n=0;n<4;n++)
      p.Hpre_kv[(size_t)(h*U_+u)*4 + n] = sigm(p.al_pre[kk]*lgread(lg,kk*24+n) + p.b_pre[kk*4+n]);
    for (int n=0;n<4;n++)
      pacc[h][n] = 2.f*sigm(p.al_post[kk]*lgread(lg,kk*24+4+n) + p.b_post[kk*4+n]);
    float M[4][4];
    for (int n=0;n<4;n++)
      for (int m=0;m<4;m++)
        M[n][m] = expf(p.al_res[kk]*lgread(lg,kk*24+8+n*4+m) + p.b_res[kk*16+n*4+m]);
    for (int it=0; it<6; it++){
      for (int n=0;n<4;n++){ float s=M[n][0]+M[n][1]+M[n][2]+M[n][3]; float r=1.f/s;
        for(int m=0;m<4;m++) M[n][m]*=r; }
      for (int m=0;m<4;m++){ float s=M[0][m]+M[1][m]+M[2][m]+M[3][m]; float r=1.f/s;
        for(int n=0;n<4;n++) M[n][m]*=r; }
    }
    for (int n=0;n<4;n++) for (int m=0;m<4;m++) racc[h][n*4+m] = M[n][m];
  }
  __syncthreads();
  if (tid < 16){
    float s=0; for (int h=0;h<8;h++) s += racc[h][tid];
    p.Hres[(size_t)u*16 + tid] = s * 0.125f;
  }
  if (tid < 4){
    float s=0; for (int h=0;h<8;h++) s += pacc[h][tid];
    p.Hpost[(size_t)u*4 + tid] = s * 0.125f;
  }
}

// h_e rows; BF=1 writes bf16, BF=0 f32
template<int BF>
__global__ void k_he(P p){
  int id = blockIdx.x;
  int path = id >> 13;
  int h = (id >> 10) & 7;
  int u = id & 1023;
  int b = u>>9, t = u&511;
  int sel = path ? p.kvsel[h*U_+u] : p.qsel[h*U_+u];
  int k = h*E_ + sel;
  const float* Hp = (path ? p.Hpre_kv : p.Hpre_q) + (size_t)(h*U_+u)*4;
  float w0=Hp[0], w1=Hp[1], w2=Hp[2], w3=Hp[3];
  float v[4];
  float ss = 0;
  int tid = threadIdx.x;
  #pragma unroll
  for (int j=0;j<4;j++){
    int d = tid + j*256;
    float s0 = p.stream[(((size_t)(b*N_+0)*T_)+t)*D_ + d];
    float s1 = p.stream[(((size_t)(b*N_+1)*T_)+t)*D_ + d];
    float s2 = p.stream[(((size_t)(b*N_+2)*T_)+t)*D_ + d];
    float s3 = p.stream[(((size_t)(b*N_+3)*T_)+t)*D_ + d];
    v[j] = w0*s0 + w1*s1 + w2*s2 + w3*s3;
    ss += v[j]*v[j];
  }
  __shared__ float sm[8];
  ss = block_reduce_sum(ss, sm);
  float sc = rsqrtf(ss/(float)D_ + 1e-8f);
  #pragma unroll
  for (int j=0;j<4;j++){
    int d = tid + j*256;
    float o = v[j]*sc*p.bn_w[(size_t)k*D_ + d];
    if (BF){
      u16* out = (path ? p.he_kvB : p.he_qB) + (size_t)(h*U_+u)*D_;
      out[d] = f2b(o);
    } else {
      float* out = (path ? p.he_kvF : p.he_qF) + (size_t)(h*U_+u)*D_;
      out[d] = o;
    }
  }
}

__global__ void k_stage2(P p){
  int id = blockIdx.x;
  int h = id >> 10, u = id & 1023;
  int t = u & 511;
  int k = h*E_ + p.kvsel[h*U_+u];
  size_t base = (size_t)(h*U_+u);
  __shared__ float s_au[DA_], s_bu[DA_], s_lk[R_], s_lv[R_], s_kl[64], s_vl[64];
  int tid = threadIdx.x;
  if (tid < DA_){ s_au[tid] = p.aup[base*DA_+tid]; s_bu[tid] = p.bup[base*DA_+tid]; }
  if (tid < R_){ s_lk[tid] = p.la_k[base*R_+tid]; s_lv[tid] = p.la_v[base*R_+tid]; }
  if (tid >= 64 && tid < 128){
    s_kl[tid-64] = p.kv_lin[base*128 + (tid-64)];
    s_vl[tid-64] = p.kv_lin[base*128 + 64 + (tid-64)];
  }
  __syncthreads();
  {
    float acc = 0;
    const float* W = p.a_dn + (size_t)k*DA_*DKP_;
    for (int a=0;a<DA_;a++) acc += s_au[a]*W[a*DKP_ + tid];
    p.a_buf[base*DKP_ + tid] = sigm(acc);
  }
  if (tid == 0){
    float acc = 0;
    const float* W = p.b_dn + (size_t)k*DA_;
    for (int a=0;a<DA_;a++) acc += s_bu[a]*W[a];
    p.b_buf[base] = sigm(acc);
  }
  if (tid < 64){
    int o = tid;
    float lbk=0.f, lbv=0.f;
    for (int r=0;r<R_;r++){
      lbk += s_lk[r]*p.lB_k[((size_t)k*R_+r)*DK_ + o];
      lbv += s_lv[r]*p.lB_v[((size_t)k*R_+r)*DV_ + o];
    }
    float kl = s_kl[o] + lbk;
    float ss = kl*kl;
    for (int off=1; off<64; off<<=1) ss += __shfl_xor(ss, off, 64);
    float kp = kl * rsqrtf(ss + 1e-12f);
    float mu = softplus_(kp);
    float ph = (float)t * p.freqs[o] - 6.2831855f * sigm(p.pope_delta[o]);
    p.k_buf[base*DKP_ + o]      = mu * cosf(ph);
    p.k_buf[base*DKP_ + 64 + o] = mu * sinf(ph);
    p.v_buf[base*DV_ + o] = s_vl[o] + lbv;
  }
}

__global__ void k_stage2q(P p){
  int id = blockIdx.x;
  int h = id >> 10, u = id & 1023;
  int t = u & 511;
  int sel = p.qsel[h*U_+u];
  size_t base = (size_t)(h*U_+u);
  int o = threadIdx.x;
  if (sel == 0){
    p.q_buf[base*DKP_ + o] = 0.f;
    p.q_buf[base*DKP_ + 64 + o] = 0.f;
    return;
  }
  int k = h*E_ + sel;
  float lbq = 0.f;
  for (int r=0;r<R_;r++) lbq += p.la_q[base*R_+r]*p.lB_q[((size_t)k*R_+r)*DK_+o];
  float ql = p.q_lin[base*64 + o] + lbq;
  float ss = ql*ql;
  for (int off=1; off<64; off<<=1) ss += __shfl_xor(ss, off, 64);
  float qp = ql*rsqrtf(ss + 1e-12f);
  float mu = softplus_(qp);
  float ph = (float)t * p.freqs[o];
  p.q_buf[base*DKP_ + o]      = mu*cosf(ph);
  p.q_buf[base*DKP_ + 64 + o] = mu*sinf(ph);
}

// KDA delta-rule scan: 3 barriers/step + register prefetch of t+1
__global__ __launch_bounds__(512) void k_scan(P p){
  int h = blockIdx.x >> 1, b = blockIdx.x & 1;
  int tid = threadIdx.x;
  int e = tid & 63, d8 = tid >> 6;
  float S[16];
  #pragma unroll
  for (int i=0;i<16;i++) S[i]=0.f;
  __shared__ float sq[128], sk[128], sa[128], sv[64];
  __shared__ float sb[1];
  __shared__ float part[8][64];
  __shared__ float part2[8][64];
  float r0=0.f, r1=0.f;
  {
    size_t base = (size_t)(h*U_ + b*T_);
    if (tid < 128){ r0 = p.q_buf[base*128+tid]; r1 = p.k_buf[base*128+tid]; }
    else if (tid < 256){ r0 = p.a_buf[base*128 + (tid-128)]; }
    else if (tid < 320){ r0 = p.v_buf[base*64 + (tid-256)]; }
    else if (tid == 320){ r0 = p.b_buf[base]; }
  }
  for (int t=0;t<T_;t++){
    if (tid < 128){ sq[tid]=r0; sk[tid]=r1; }
    else if (tid < 256){ sa[tid-128]=r0; }
    else if (tid < 320){ sv[tid-256]=r0; }
    else if (tid == 320){ sb[0]=r0; }
    __syncthreads();
    if (t+1 < T_){
      size_t base = (size_t)(h*U_ + b*T_ + t+1);
      if (tid < 128){ r0 = p.q_buf[base*128+tid]; r1 = p.k_buf[base*128+tid]; }
      else if (tid < 256){ r0 = p.a_buf[base*128 + (tid-128)]; }
      else if (tid < 320){ r0 = p.v_buf[base*64 + (tid-256)]; }
      else if (tid == 320){ r0 = p.b_buf[base]; }
    }
    int db = d8*16;
    float pa = 0.f;
    #pragma unroll
    for (int i=0;i<16;i++) pa += sk[db+i]*sa[db+i]*S[i];
    part[d8][e] = pa;
    __syncthreads();
    float w = sv[e];
    #pragma unroll
    for (int j=0;j<8;j++) w -= part[j][e];
    float bs = sb[0];
    float o = 0.f;
    #pragma unroll
    for (int i=0;i<16;i++){
      S[i] = sa[db+i]*S[i] + bs*sk[db+i]*w;
      o += sq[db+i]*S[i];
    }
    part2[d8][e] = o;
    __syncthreads();
    if (tid < 64){
      float s=0;
      #pragma unroll
      for (int j=0;j<8;j++) s += part2[j][tid];
      p.attn[(size_t)(b*T_+t)*CC_ + h*64 + tid] = s;
    }
  }
}

__global__ void k_final(P p){
  int u = blockIdx.x, b=u>>9, t=u&511;
  __shared__ float hr[16], hp[4];
  if (threadIdx.x < 16) hr[threadIdx.x] = p.Hres[(size_t)u*16+threadIdx.x];
  if (threadIdx.x < 4)  hp[threadIdx.x] = p.Hpost[(size_t)u*4+threadIdx.x];
  __syncthreads();
  for (int d = threadIdx.x; d < D_; d += 256){
    float yv = p.y[(size_t)u*D_ + d];
    float sm0 = p.stream[(((size_t)(b*N_+0)*T_)+t)*D_ + d];
    float sm1 = p.stream[(((size_t)(b*N_+1)*T_)+t)*D_ + d];
    float sm2 = p.stream[(((size_t)(b*N_+2)*T_)+t)*D_ + d];
    float sm3 = p.stream[(((size_t)(b*N_+3)*T_)+t)*D_ + d];
    #pragma unroll
    for (int n=0;n<4;n++){
      float v = hr[n*4+0]*sm0 + hr[n*4+1]*sm1 + hr[n*4+2]*sm2 + hr[n*4+3]*sm3 + hp[n]*yv;
      p.out[(((size_t)(b*N_+n)*T_)+t)*D_ + d] = v;
    }
  }
}

// ============================ host launch ============================

extern "C" void kernel_launch(void* const* d_in, const int* in_sizes, int n_in,
                              void* d_out, int out_size, void* d_ws, size_t ws_size,
                              hipStream_t stream){
  P p;
  p.stream = (const float*)d_in[0];
  p.freqs = (const float*)d_in[1];
  p.pope_delta = (const float*)d_in[2];
  p.W_q = (const float*)d_in[3]; p.W_k = (const float*)d_in[4]; p.W_v = (const float*)d_in[5];
  p.q_rw = (const float*)d_in[6]; p.kv_rw = (const float*)d_in[7];
  p.lA_q = (const float*)d_in[8];  p.lB_q = (const float*)d_in[9];
  p.lA_k = (const float*)d_in[10]; p.lB_k = (const float*)d_in[11];
  p.lA_v = (const float*)d_in[12]; p.lB_v = (const float*)d_in[13];
  p.a_up = (const float*)d_in[14]; p.a_dn = (const float*)d_in[15];
  p.b_up = (const float*)d_in[16]; p.b_dn = (const float*)d_in[17];
  p.mhc_norm = (const float*)d_in[18];
  p.phi_pre = (const float*)d_in[19]; p.phi_post = (const float*)d_in[20]; p.phi_res = (const float*)d_in[21];
  p.b_pre = (const float*)d_in[22]; p.b_post = (const float*)d_in[23]; p.b_res = (const float*)d_in[24];
  p.al_pre = (const float*)d_in[25]; p.al_post = (const float*)d_in[26]; p.al_res = (const float*)d_in[27];
  p.bn_w = (const float*)d_in[28];
  p.W_pre = (const float*)d_in[29]; p.W_o = (const float*)d_in[30];
  p.W_pg1 = (const float*)d_in[31]; p.W_pg2 = (const float*)d_in[32];
  p.out = (float*)d_out;

  char* w = (char*)d_ws;
  size_t off = 0;
  auto alloc = [&](size_t bytes)->void*{
    void* r = w + off;
    off = (off + bytes + 255) & ~(size_t)255;
    return r;
  };
  // ---- common buffers ----
  p.qsel   = (int*)alloc(H_*U_*4);
  p.kvsel  = (int*)alloc(H_*U_*4);
  p.qcnt   = (int*)alloc(HE_*4);
  p.kvcnt  = (int*)alloc(HE_*4);
  p.qlist  = (int*)alloc((size_t)HE_*U_*4);
  p.kvlist = (int*)alloc((size_t)HE_*U_*4);
  p.scale  = (float*)alloc(U_*4);
  p.mhc_partial = (float*)alloc((size_t)4*U_*1152*4);
  p.Hpre_q  = (float*)alloc((size_t)H_*U_*4*4);
  p.Hpre_kv = (float*)alloc((size_t)H_*U_*4*4);
  p.Hres    = (float*)alloc((size_t)U_*16*4);
  p.Hpost   = (float*)alloc((size_t)U_*4*4);
  p.kv_lin  = (float*)alloc((size_t)H_*U_*128*4);
  p.aup     = (float*)alloc((size_t)H_*U_*DA_*4);
  p.bup     = (float*)alloc((size_t)H_*U_*DA_*4);
  p.pre_logit  = (float*)alloc((size_t)U_*CC_*4);
  p.post_logit = (float*)alloc((size_t)U_*D_*4);
  p.la_k    = (float*)alloc((size_t)H_*U_*R_*4);
  p.la_v    = (float*)alloc((size_t)H_*U_*R_*4);
  p.la_q    = (float*)alloc((size_t)H_*U_*R_*4);
  p.q_lin   = (float*)alloc((size_t)H_*U_*64*4);
  p.a_buf   = (float*)alloc((size_t)H_*U_*DKP_*4);
  p.b_buf   = (float*)alloc((size_t)H_*U_*4);
  p.q_buf   = (float*)alloc((size_t)H_*U_*DKP_*4);
  p.k_buf   = (float*)alloc((size_t)H_*U_*DKP_*4);
  p.v_buf   = (float*)alloc((size_t)H_*U_*DV_*4);
  p.attn    = (float*)alloc((size_t)U_*CC_*4);
  p.y       = (float*)alloc((size_t)U_*D_*4);
  size_t common_off = off;

  // ---- try MFMA layout ----
  p.he_kvB = (u16*)alloc((size_t)H_*U_*D_*2);
  p.he_qB  = (u16*)alloc((size_t)H_*U_*D_*2);
  p.pgB    = (u16*)alloc((size_t)H_*U_*320*2);
  p.Bt0    = (u16*)alloc((size_t)1152*4096*2);
  p.Bt1    = (u16*)alloc((size_t)HE_*1216*1024*2);
  p.Bt2    = (u16*)alloc((size_t)HE_*128*1024*2);
  p.Bt3    = (u16*)alloc((size_t)HE_*1024*320*2);
  p.Bt4    = (u16*)alloc((size_t)1024*512*2);
  bool mfma = (off <= ws_size);

  if (!mfma){
    off = common_off;
    p.phiT   = (float*)alloc((size_t)ND_*1152*4);
    p.he_kvF = (float*)alloc((size_t)H_*U_*D_*4);
    p.he_qF  = (float*)alloc((size_t)H_*U_*D_*4);
    p.pgF    = (float*)alloc((size_t)H_*U_*DPG_*4);
    p.WqT    = (float*)alloc((size_t)H_*D_*64*4);
    p.WkT    = (float*)alloc((size_t)H_*D_*64*4);
    p.WvT    = (float*)alloc((size_t)H_*D_*64*4);
    p.WoT    = (float*)alloc((size_t)CC_*D_*4);
    if (off > ws_size) return;
  }

  hipMemsetAsync(p.qcnt, 0, HE_*4, stream);
  hipMemsetAsync(p.kvcnt, 0, HE_*4, stream);
  hipMemsetAsync(p.pre_logit, 0, (size_t)U_*CC_*4, stream);
  hipMemsetAsync(p.post_logit, 0, (size_t)U_*D_*4, stream);

  if (mfma){
    hipMemsetAsync(p.pgB, 0, (size_t)H_*U_*320*2, stream);
    hipMemsetAsync(p.Bt2, 0, (size_t)HE_*128*1024*2, stream);
    // weight preps
    k_prep0<<<1152,256,0,stream>>>(p);
    k_prep1d<<<dim3(150,48),256,0,stream>>>(p);
    size_t b1s = (size_t)1216*1024;
    k_prept<<<dim3(32, 4,48),256,0,stream>>>(p.a_up,  (long)1024*DA_, DA_, DA_, p.Bt1+ 128*1024, b1s, 1024, 1024, 1024);
    k_prept<<<dim3(32, 4,48),256,0,stream>>>(p.b_up,  (long)1024*DA_, DA_, DA_, p.Bt1+ 231*1024, b1s, 1024, 1024, 1024);
    k_prept<<<dim3(32,16,48),256,0,stream>>>(p.W_pre, (long)1024*CC_, CC_, CC_, p.Bt1+ 334*1024, b1s, 1024, 1024, 1024);
    k_prept<<<dim3(32,10,48),256,0,stream>>>(p.W_pg1, (long)1024*DPG_,DPG_,DPG_,p.Bt1+ 846*1024, b1s, 1024, 1024, 1024);
    k_prept<<<dim3(32, 1,48),256,0,stream>>>(p.lA_k,  (long)1024*R_,  R_,  R_,  p.Bt1+1162*1024, b1s, 1024, 1024, 1024);
    k_prept<<<dim3(32, 1,48),256,0,stream>>>(p.lA_v,  (long)1024*R_,  R_,  R_,  p.Bt1+1178*1024, b1s, 1024, 1024, 1024);
    k_prep2d<<<dim3(64,48),256,0,stream>>>(p);
    k_prept<<<dim3(32, 1,48),256,0,stream>>>(p.lA_q,  (long)1024*R_,  R_,  R_,  p.Bt2+  64*1024, (long)128*1024, 1024, 1024, 1024);
    k_prept<<<dim3(10,32,48),256,0,stream>>>(p.W_pg2, (long)DPG_*1024,1024,1024,p.Bt3,           (long)1024*320,  320,  320,  316);
    k_prep4<<<1024,256,0,stream>>>(p);

    k_route<<<U_,256,0,stream>>>(p);
    k_xscale<<<U_,256,0,stream>>>(p);
    k_mgemm<0><<<dim3(9,8,4),256,0,stream>>>(p);
    k_mhcsel<<<U_,64,0,stream>>>(p);
    k_he<1><<<2*H_*U_,256,0,stream>>>(p);
    k_mgemm<1><<<dim3(10,8,48),256,0,stream>>>(p);
    k_mgemm<2><<<dim3(1,8,48),256,0,stream>>>(p);
    k_stage2<<<H_*U_,128,0,stream>>>(p);
    k_stage2q<<<H_*U_,64,0,stream>>>(p);
    k_mgemm<3><<<dim3(8,8,48),256,0,stream>>>(p);
    k_scan<<<16,512,0,stream>>>(p);
    k_mgemm<4><<<dim3(8,8,1),256,0,stream>>>(p);
    k_final<<<U_,256,0,stream>>>(p);
  } else {
    k_tr<<<dim3(32,2,8),256,0,stream>>>(p.W_q, p.WqT, 64, 1024);
    k_tr<<<dim3(32,2,8),256,0,stream>>>(p.W_k, p.WkT, 64, 1024);
    k_tr<<<dim3(32,2,8),256,0,stream>>>(p.W_v, p.WvT, 64, 1024);
    k_tr<<<dim3(16,32,1),256,0,stream>>>(p.W_o, p.WoT, 1024, 512);
    k_phiT<<<1152,256,0,stream>>>(p);
    k_route<<<U_,256,0,stream>>>(p);
    k_xscale<<<U_,256,0,stream>>>(p);
    k_gemm_f32<0><<<dim3(9,8,4),256,0,stream>>>(p);
    k_mhcsel<<<U_,64,0,stream>>>(p);
    k_he<0><<<2*H_*U_,256,0,stream>>>(p);
    k_gemm_f32<1><<<dim3(10,8,48),256,0,stream>>>(p);
    k_gemm_f32<2><<<dim3(1,8,48),256,0,stream>>>(p);
    k_stage2<<<H_*U_,128,0,stream>>>(p);
    k_stage2q<<<H_*U_,64,0,stream>>>(p);
    k_gemm_f32<3><<<dim3(8,8,48),256,0,stream>>>(p);
    k_scan<<<16,512,0,stream>>>(p);
    k_gemm_f32<4><<<dim3(8,8,1),256,0,stream>>>(p);
    k_final<<<U_,256,0,stream>>>(p);
  }
}